// Round 1
// baseline (981.142 us; speedup 1.0000x reference)
//
#include <hip/hip_runtime.h>

#define NB   32
#define NN   2048
#define CINx 64
#define COUTx 128
#define ADJ_EPS 1e-6f
#define BN_EPS  1e-5f

// workspace layout (in floats)
#define XS_LEN  ((size_t)NB * NN * CINx)   // 4,194,304 floats = 16 MB
#define BN1_OFF (XS_LEN)                   // 128
#define BN2_OFF (XS_LEN + 128)             // 128
#define SC_OFF  (XS_LEN + 256)             // 128
#define SH_OFF  (XS_LEN + 384)             // 128

// ---------------- K1: row-sum of A, write xs = x * 1/(rowsum+eps) ----------
__global__ __launch_bounds__(256) void k1_rowsum(const float* __restrict__ A,
                                                 const float* __restrict__ x,
                                                 float* __restrict__ xs) {
    int row  = blockIdx.x * 4 + (threadIdx.x >> 6);   // one wave per row
    int lane = threadIdx.x & 63;
    const float4* a4 = reinterpret_cast<const float4*>(A + (size_t)row * NN);
    float s = 0.f;
#pragma unroll
    for (int i = 0; i < 8; ++i) {
        float4 v = a4[i * 64 + lane];
        s += (v.x + v.y) + (v.z + v.w);
    }
#pragma unroll
    for (int off = 32; off > 0; off >>= 1) s += __shfl_down(s, off);
    float inv = 1.f / (__shfl(s, 0) + ADJ_EPS);
    // lane == channel (CIN == 64)
    xs[(size_t)row * CINx + lane] = x[(size_t)row * CINx + lane] * inv;
}

// ---------------- K2: xg = xs^T @ A  (per (b, m-tile)), epilogue h = W@xg+b,
//                   BN partial sums, h stored to d_out in [b,m,o] layout -----
#define FMA4(d, s, v)                    \
    d.x = fmaf(s, v.x, d.x);             \
    d.y = fmaf(s, v.y, d.y);             \
    d.z = fmaf(s, v.z, d.z);             \
    d.w = fmaf(s, v.w, d.w)

__global__ __launch_bounds__(256, 2) void k2_gemm(const float* __restrict__ A,
                                                  const float* __restrict__ xs,
                                                  const float* __restrict__ W,
                                                  const float* __restrict__ bias,
                                                  float* __restrict__ hout,
                                                  float* __restrict__ bnsum,
                                                  float* __restrict__ bnsumsq) {
    __shared__ float Atile[64 * 128];   // also reused as xg tile in epilogue
    __shared__ float XSt[64 * 64];
    __shared__ float bn1[256], bn2[256];

    // XCD swizzle: all 16 m-tiles of a batch land on the same XCD (round-robin
    // dispatch): keeps xs[b] (512 KB) L2-resident.
    int b  = blockIdx.x & 31;
    int m0 = (blockIdx.x >> 5) * 128;
    int t  = threadIdx.x;

    float4 acc[8];
#pragma unroll
    for (int i = 0; i < 8; ++i) acc[i] = make_float4(0.f, 0.f, 0.f, 0.f);

    const int ml = (t & 31) * 4;   // 4 consecutive m per thread
    const int c0 = (t >> 5) * 8;   // 8 consecutive c per thread

    for (int n0 = 0; n0 < NN; n0 += 64) {
        __syncthreads();
        // stage A[b, n0:n0+64, m0:m0+128]  (2048 float4, 8 per thread)
#pragma unroll
        for (int i = 0; i < 8; ++i) {
            int idx = t + i * 256;
            int r = idx >> 5, c4 = (idx & 31) * 4;
            *reinterpret_cast<float4*>(&Atile[r * 128 + c4]) =
                *reinterpret_cast<const float4*>(
                    &A[((size_t)b * NN + n0 + r) * NN + m0 + c4]);
        }
        // stage xs[b, n0:n0+64, :]  (1024 float4, 4 per thread)
#pragma unroll
        for (int i = 0; i < 4; ++i) {
            int idx = t + i * 256;
            int r = idx >> 4, c4 = (idx & 15) * 4;
            *reinterpret_cast<float4*>(&XSt[r * 64 + c4]) =
                *reinterpret_cast<const float4*>(
                    &xs[((size_t)b * NN + n0 + r) * CINx + c4]);
        }
        __syncthreads();
#pragma unroll 8
        for (int kk = 0; kk < 64; ++kk) {
            float4 am = *reinterpret_cast<const float4*>(&Atile[kk * 128 + ml]);
            float4 xa = *reinterpret_cast<const float4*>(&XSt[kk * 64 + c0]);
            float4 xb = *reinterpret_cast<const float4*>(&XSt[kk * 64 + c0 + 4]);
            FMA4(acc[0], xa.x, am);
            FMA4(acc[1], xa.y, am);
            FMA4(acc[2], xa.z, am);
            FMA4(acc[3], xa.w, am);
            FMA4(acc[4], xb.x, am);
            FMA4(acc[5], xb.y, am);
            FMA4(acc[6], xb.z, am);
            FMA4(acc[7], xb.w, am);
        }
    }
    __syncthreads();
    // dump xg tile [64 c][128 m] into LDS (reuse Atile region)
#pragma unroll
    for (int cc = 0; cc < 8; ++cc)
        *reinterpret_cast<float4*>(&Atile[(c0 + cc) * 128 + ml]) = acc[cc];
    __syncthreads();

    // epilogue: h[o, m] = b[o] + sum_c W[o,c] * xg[c,m]; store [b,m,o]
    int o  = t & 127;
    int mq = t >> 7;                       // which half of the 128 m's
    const float* Wrow = W + o * 64;
    float bo = bias[o];
    float s1 = 0.f, s2 = 0.f;
    for (int mc = 0; mc < 4; ++mc) {
        float h[16];
#pragma unroll
        for (int i = 0; i < 16; ++i) h[i] = bo;
        for (int c = 0; c < 64; ++c) {
            float w = Wrow[c];
            const float* xgp = &Atile[c * 128 + mq * 64 + mc * 16];
            float4 g0 = *reinterpret_cast<const float4*>(&xgp[0]);
            float4 g1 = *reinterpret_cast<const float4*>(&xgp[4]);
            float4 g2 = *reinterpret_cast<const float4*>(&xgp[8]);
            float4 g3 = *reinterpret_cast<const float4*>(&xgp[12]);
            h[0]  = fmaf(w, g0.x, h[0]);  h[1]  = fmaf(w, g0.y, h[1]);
            h[2]  = fmaf(w, g0.z, h[2]);  h[3]  = fmaf(w, g0.w, h[3]);
            h[4]  = fmaf(w, g1.x, h[4]);  h[5]  = fmaf(w, g1.y, h[5]);
            h[6]  = fmaf(w, g1.z, h[6]);  h[7]  = fmaf(w, g1.w, h[7]);
            h[8]  = fmaf(w, g2.x, h[8]);  h[9]  = fmaf(w, g2.y, h[9]);
            h[10] = fmaf(w, g2.z, h[10]); h[11] = fmaf(w, g2.w, h[11]);
            h[12] = fmaf(w, g3.x, h[12]); h[13] = fmaf(w, g3.y, h[13]);
            h[14] = fmaf(w, g3.z, h[14]); h[15] = fmaf(w, g3.w, h[15]);
        }
        size_t base = ((size_t)b * NN + m0 + mq * 64 + mc * 16) * COUTx + o;
#pragma unroll
        for (int i = 0; i < 16; ++i) {
            float v = h[i];
            s1 += v;
            s2 = fmaf(v, v, s2);
            hout[base + (size_t)i * COUTx] = v;   // coalesced: lanes = consecutive o
        }
    }
    bn1[t] = s1;
    bn2[t] = s2;
    __syncthreads();
    if (t < 128) {
        atomicAdd(&bnsum[o],   bn1[t] + bn1[t + 128]);
        atomicAdd(&bnsumsq[o], bn2[t] + bn2[t + 128]);
    }
}

// ---------------- K3: finalize BN stats -> per-channel scale/shift ----------
__global__ void k3_bnstats(const float* __restrict__ bnsum,
                           const float* __restrict__ bnsumsq,
                           const float* __restrict__ gamma,
                           const float* __restrict__ beta,
                           float* __restrict__ scale,
                           float* __restrict__ shift) {
    int o = threadIdx.x;
    if (o < COUTx) {
        const float invn = 1.f / ((float)NB * (float)NN);
        float mean = bnsum[o] * invn;
        float var  = bnsumsq[o] * invn - mean * mean;   // biased variance
        float sc   = gamma[o] * rsqrtf(var + BN_EPS);
        scale[o] = sc;
        shift[o] = beta[o] - mean * sc;
    }
}

// ---------------- K4: in-place normalize + ReLU on d_out --------------------
__global__ __launch_bounds__(256) void k4_bnapply(float* __restrict__ hout,
                                                  const float* __restrict__ scale,
                                                  const float* __restrict__ shift) {
    const float4* sc4 = reinterpret_cast<const float4*>(scale);
    const float4* sh4 = reinterpret_cast<const float4*>(shift);
    float4* h4 = reinterpret_cast<float4*>(hout);
    const size_t n4 = (size_t)NB * NN * COUTx / 4;
    for (size_t idx = (size_t)blockIdx.x * blockDim.x + threadIdx.x; idx < n4;
         idx += (size_t)gridDim.x * blockDim.x) {
        int o4 = (int)(idx & 31);   // 32 float4 per 128-channel row
        float4 h = h4[idx];
        float4 s = sc4[o4];
        float4 f = sh4[o4];
        h.x = fmaxf(fmaf(h.x, s.x, f.x), 0.f);
        h.y = fmaxf(fmaf(h.y, s.y, f.y), 0.f);
        h.z = fmaxf(fmaf(h.z, s.z, f.z), 0.f);
        h.w = fmaxf(fmaf(h.w, s.w, f.w), 0.f);
        h4[idx] = h;
    }
}

extern "C" void kernel_launch(void* const* d_in, const int* in_sizes, int n_in,
                              void* d_out, int out_size, void* d_ws, size_t ws_size,
                              hipStream_t stream) {
    const float* x     = (const float*)d_in[0];
    const float* A     = (const float*)d_in[1];
    const float* W     = (const float*)d_in[2];
    const float* bvec  = (const float*)d_in[3];
    const float* gamma = (const float*)d_in[4];
    const float* beta  = (const float*)d_in[5];
    float* out = (float*)d_out;
    float* ws  = (float*)d_ws;

    float* xs      = ws;
    float* bnsum   = ws + BN1_OFF;
    float* bnsumsq = ws + BN2_OFF;
    float* scale   = ws + SC_OFF;
    float* shift   = ws + SH_OFF;

    // zero the BN accumulators (ws is poisoned 0xAA before every call)
    hipMemsetAsync(bnsum, 0, 256 * sizeof(float), stream);

    k1_rowsum<<<NB * NN / 4, 256, 0, stream>>>(A, x, xs);
    k2_gemm<<<NB * (NN / 128), 256, 0, stream>>>(A, xs, W, bvec, out, bnsum, bnsumsq);
    k3_bnstats<<<1, 128, 0, stream>>>(bnsum, bnsumsq, gamma, beta, scale, shift);
    k4_bnapply<<<2048, 256, 0, stream>>>(out, scale, shift);
}

// Round 2
// 833.475 us; speedup vs baseline: 1.1772x; 1.1772x over previous
//
#include <hip/hip_runtime.h>

#define NB   32
#define NN   2048
#define CIN  64
#define COUT 128
#define ADJ_EPS 1e-6f
#define BN_EPS  1e-5f

typedef __attribute__((ext_vector_type(8))) short short8;
typedef __attribute__((ext_vector_type(4))) float floatx4;

// ws layout (float units):
// [0..127] bnsum | [128..255] bnsumsq | [256..383] scale | [384..511] shift
// [512 ...] xsT bf16 as ushort: NB*CIN*NN ushorts = 8 MB
#define BN1_OFF 0
#define BN2_OFF 128
#define SC_OFF  256
#define SH_OFF  384
#define XST_OFF 512

static __device__ __forceinline__ ushort f2bf(float f) {
    union { float f; unsigned u; } v; v.f = f;
    unsigned r = v.u + 0x7FFFu + ((v.u >> 16) & 1u);   // RNE
    return (ushort)(r >> 16);
}
static __device__ __forceinline__ float bf2f(ushort u) {
    return __uint_as_float(((unsigned)u) << 16);
}

// ---------------- K1: rowsum(A) -> inv; write xsT[b][c][n] = bf16(x[n][c]*inv[n])
__global__ __launch_bounds__(256) void k1_norm(const float* __restrict__ A,
                                               const float* __restrict__ x,
                                               ushort* __restrict__ xsT) {
    __shared__ float invr[128];
    __shared__ __align__(16) ushort xsb[64 * 136];   // [c][n] bf16, stride 136
    int b  = blockIdx.x & 31;                        // XCD swizzle
    int n0 = (blockIdx.x >> 5) * 128;
    int t  = threadIdx.x;
    int w  = t >> 6, lane = t & 63;

    // phase 1: row sums (one wave, two rows in flight for MLP)
    for (int i = 0; i < 32; i += 2) {
        int r0 = w * 32 + i;
        const float4* a0 = (const float4*)(A + ((size_t)b * NN + n0 + r0) * NN);
        const float4* a1 = (const float4*)(A + ((size_t)b * NN + n0 + r0 + 1) * NN);
        float s0 = 0.f, s1 = 0.f;
#pragma unroll
        for (int j = 0; j < 8; ++j) {
            float4 v0 = a0[j * 64 + lane];
            float4 v1 = a1[j * 64 + lane];
            s0 += (v0.x + v0.y) + (v0.z + v0.w);
            s1 += (v1.x + v1.y) + (v1.z + v1.w);
        }
#pragma unroll
        for (int off = 32; off; off >>= 1) {
            s0 += __shfl_down(s0, off);
            s1 += __shfl_down(s1, off);
        }
        if (lane == 0) {
            invr[r0]     = 1.f / (s0 + ADJ_EPS);
            invr[r0 + 1] = 1.f / (s1 + ADJ_EPS);
        }
    }
    __syncthreads();
    // phase 2: scale + transpose into LDS (pairs of n packed per 4B write)
    {
        int c = t & 63, nh = t >> 6;
#pragma unroll
        for (int i = 0; i < 16; ++i) {
            int dn = nh * 32 + i * 2;
            float x0 = x[((size_t)b * NN + n0 + dn) * CIN + c] * invr[dn];
            float x1 = x[((size_t)b * NN + n0 + dn + 1) * CIN + c] * invr[dn + 1];
            ushort2 p; p.x = f2bf(x0); p.y = f2bf(x1);
            *(ushort2*)&xsb[c * 136 + dn] = p;
        }
    }
    __syncthreads();
    // phase 3: b128 copy-out to xsT[b][c][n0:n0+128]
    {
        int c = t >> 2, s = t & 3;
#pragma unroll
        for (int i = 0; i < 4; ++i) {
            short8 v = *(const short8*)&xsb[c * 136 + (s * 4 + i) * 8];
            *(short8*)&xsT[((size_t)b * CIN + c) * NN + n0 + (s * 4 + i) * 8] = v;
        }
    }
}

// ---------------- K2: xg = xs^T @ A via bf16 MFMA; epilogue h = W@xg + b,
//                  BN partials; h stored to d_out in [b,m,o] layout ----------
__global__ __launch_bounds__(256, 2) void k2_gemm(const float* __restrict__ A,
                                                  const ushort* __restrict__ xsT,
                                                  const float* __restrict__ W,
                                                  const float* __restrict__ bias,
                                                  float* __restrict__ hout,
                                                  float* __restrict__ bnsum,
                                                  float* __restrict__ bnsumsq) {
    __shared__ __align__(16) ushort Att[128 * 72];   // adjacency^T tile [m][n]
    __shared__ __align__(16) ushort Xst[64 * 72];    // xs^T tile [c][n]
    __shared__ __align__(16) float  xg[64 * 128];    // result tile [c][m]
    __shared__ __align__(16) ushort2 Wb[32 * 128];   // W bf16, [c-pair][o]
    __shared__ float bn1[256], bn2[256];

    int b  = blockIdx.x & 31;                        // XCD swizzle: batch -> XCD
    int m0 = (blockIdx.x >> 5) * 128;
    int t  = threadIdx.x;
    int w  = t >> 6, lane = t & 63;
    int l15 = lane & 15, q = lane >> 4;

    // one-time: stage W -> Wb bf16 (interleaved c-pairs for ushort2 epilogue reads)
    {
        ushort* wbu = (ushort*)Wb;
        int c = t & 63, o0 = (t >> 6) * 32;
#pragma unroll
        for (int p = 0; p < 32; ++p) {
            int o = o0 + p;
            wbu[(c >> 1) * 256 + o * 2 + (c & 1)] = f2bf(W[o * CIN + c]);
        }
    }

    floatx4 acc[4][2];
#pragma unroll
    for (int ct = 0; ct < 4; ++ct)
#pragma unroll
        for (int j = 0; j < 2; ++j) {
            floatx4 z = {0.f, 0.f, 0.f, 0.f};
            acc[ct][j] = z;
        }

    for (int n0 = 0; n0 < NN; n0 += 64) {
        __syncthreads();
        // stage Att[m][n] (transpose of A[b, n0:n0+64, m0:m0+128]) in bf16
        {
            int mm = t & 127, nh = t >> 7;
            const float* Ab = A + ((size_t)b * NN + n0) * NN + m0 + mm;
#pragma unroll
            for (int i = 0; i < 16; ++i) {
                int dn = nh * 32 + i * 2;
                float a0 = Ab[(size_t)dn * NN];
                float a1 = Ab[(size_t)(dn + 1) * NN];
                ushort2 p; p.x = f2bf(a0); p.y = f2bf(a1);
                *(ushort2*)&Att[mm * 72 + dn] = p;
            }
        }
        // stage Xst[c][n] straight from xsT (already bf16, K-contiguous)
        {
            int c = t >> 2, s = t & 3;
#pragma unroll
            for (int i = 0; i < 2; ++i) {
                short8 v = *(const short8*)&xsT[((size_t)b * CIN + c) * NN + n0 + (s * 2 + i) * 8];
                *(short8*)&Xst[c * 72 + (s * 2 + i) * 8] = v;
            }
        }
        __syncthreads();
#pragma unroll
        for (int kk = 0; kk < 64; kk += 32) {
            short8 af[4], bfr[2];
#pragma unroll
            for (int ct = 0; ct < 4; ++ct)
                af[ct] = *(const short8*)&Xst[(ct * 16 + l15) * 72 + kk + q * 8];
#pragma unroll
            for (int j = 0; j < 2; ++j)
                bfr[j] = *(const short8*)&Att[((w * 2 + j) * 16 + l15) * 72 + kk + q * 8];
#pragma unroll
            for (int ct = 0; ct < 4; ++ct)
#pragma unroll
                for (int j = 0; j < 2; ++j)
                    acc[ct][j] = __builtin_amdgcn_mfma_f32_16x16x32_bf16(
                        af[ct], bfr[j], acc[ct][j], 0, 0, 0);
        }
    }
    __syncthreads();
    // dump accumulators -> xg[c][m]  (D layout: col=lane&15, row=quad*4+reg)
#pragma unroll
    for (int ct = 0; ct < 4; ++ct)
#pragma unroll
        for (int j = 0; j < 2; ++j) {
            int col = (w * 2 + j) * 16 + l15;
#pragma unroll
            for (int r = 0; r < 4; ++r)
                xg[(ct * 16 + q * 4 + r) * 128 + col] = acc[ct][j][r];
        }
    __syncthreads();

    // epilogue: h[o,m] = b[o] + sum_c W[o,c]*xg[c,m]; store [b,m,o]; BN partials
    int o  = t & 127;
    int mq = t >> 7;
    float bo = bias[o];
    float s1 = 0.f, s2 = 0.f;
    for (int mc = 0; mc < 4; ++mc) {
        float h[16];
#pragma unroll
        for (int i = 0; i < 16; ++i) h[i] = bo;
#pragma unroll
        for (int c2 = 0; c2 < 32; ++c2) {
            ushort2 wp = Wb[c2 * 128 + o];
            float w0 = bf2f(wp.x), w1 = bf2f(wp.y);
            const float* x0p = &xg[(2 * c2) * 128 + mq * 64 + mc * 16];
            const float* x1p = &xg[(2 * c2 + 1) * 128 + mq * 64 + mc * 16];
#pragma unroll
            for (int v = 0; v < 4; ++v) {
                float4 g0 = *(const float4*)&x0p[v * 4];
                float4 g1 = *(const float4*)&x1p[v * 4];
                h[v * 4 + 0] = fmaf(w0, g0.x, fmaf(w1, g1.x, h[v * 4 + 0]));
                h[v * 4 + 1] = fmaf(w0, g0.y, fmaf(w1, g1.y, h[v * 4 + 1]));
                h[v * 4 + 2] = fmaf(w0, g0.z, fmaf(w1, g1.z, h[v * 4 + 2]));
                h[v * 4 + 3] = fmaf(w0, g0.w, fmaf(w1, g1.w, h[v * 4 + 3]));
            }
        }
        size_t base = ((size_t)b * NN + m0 + mq * 64 + mc * 16) * COUT + o;
#pragma unroll
        for (int i = 0; i < 16; ++i) {
            float v = h[i];
            s1 += v;
            s2 = fmaf(v, v, s2);
            hout[base + (size_t)i * COUT] = v;   // lanes = consecutive o: coalesced
        }
    }
    bn1[t] = s1;
    bn2[t] = s2;
    __syncthreads();
    if (t < 128) {
        atomicAdd(&bnsum[o],   bn1[t] + bn1[t + 128]);
        atomicAdd(&bnsumsq[o], bn2[t] + bn2[t + 128]);
    }
}

// ---------------- K3: finalize BN stats ------------------------------------
__global__ void k3_bnstats(const float* __restrict__ bnsum,
                           const float* __restrict__ bnsumsq,
                           const float* __restrict__ gamma,
                           const float* __restrict__ beta,
                           float* __restrict__ scale,
                           float* __restrict__ shift) {
    int o = threadIdx.x;
    if (o < COUT) {
        const float invn = 1.f / ((float)NB * (float)NN);
        float mean = bnsum[o] * invn;
        float var  = bnsumsq[o] * invn - mean * mean;
        float sc   = gamma[o] * rsqrtf(var + BN_EPS);
        scale[o] = sc;
        shift[o] = beta[o] - mean * sc;
    }
}

// ---------------- K4: in-place BN apply + ReLU ------------------------------
__global__ __launch_bounds__(256) void k4_bnapply(float* __restrict__ hout,
                                                  const float* __restrict__ scale,
                                                  const float* __restrict__ shift) {
    const float4* sc4 = (const float4*)scale;
    const float4* sh4 = (const float4*)shift;
    float4* h4 = (float4*)hout;
    const size_t n4 = (size_t)NB * NN * COUT / 4;
    for (size_t idx = (size_t)blockIdx.x * blockDim.x + threadIdx.x; idx < n4;
         idx += (size_t)gridDim.x * blockDim.x) {
        int o4 = (int)(idx & 31);
        float4 h = h4[idx];
        float4 s = sc4[o4];
        float4 f = sh4[o4];
        h.x = fmaxf(fmaf(h.x, s.x, f.x), 0.f);
        h.y = fmaxf(fmaf(h.y, s.y, f.y), 0.f);
        h.z = fmaxf(fmaf(h.z, s.z, f.z), 0.f);
        h.w = fmaxf(fmaf(h.w, s.w, f.w), 0.f);
        h4[idx] = h;
    }
}

extern "C" void kernel_launch(void* const* d_in, const int* in_sizes, int n_in,
                              void* d_out, int out_size, void* d_ws, size_t ws_size,
                              hipStream_t stream) {
    const float* x     = (const float*)d_in[0];
    const float* A     = (const float*)d_in[1];
    const float* W     = (const float*)d_in[2];
    const float* bvec  = (const float*)d_in[3];
    const float* gamma = (const float*)d_in[4];
    const float* beta  = (const float*)d_in[5];
    float* out = (float*)d_out;
    float* ws  = (float*)d_ws;

    float*  bnsum   = ws + BN1_OFF;
    float*  bnsumsq = ws + BN2_OFF;
    float*  scale   = ws + SC_OFF;
    float*  shift   = ws + SH_OFF;
    ushort* xsT     = (ushort*)(ws + XST_OFF);

    hipMemsetAsync(bnsum, 0, 256 * sizeof(float), stream);

    k1_norm<<<NB * (NN / 128), 256, 0, stream>>>(A, x, xsT);
    k2_gemm<<<NB * (NN / 128), 256, 0, stream>>>(A, xsT, W, bvec, out, bnsum, bnsumsq);
    k3_bnstats<<<1, 128, 0, stream>>>(bnsum, bnsumsq, gamma, beta, scale, shift);
    k4_bnapply<<<2048, 256, 0, stream>>>(out, scale, shift);
}